// Round 1
// baseline (1174.219 us; speedup 1.0000x reference)
//
#include <hip/hip_runtime.h>

// Problem: B=2, H=16, S=2048, DK=DV=64, fp32.
// out = [context (B,H,S,64) | attention (B,H,S,S)] flat-concatenated.
// Softmax has no max-subtraction: scores bounded (~|s|<8), exp() safe in fp32.
// Mask: int32 (bool->int), shape (B,1,S,S); mask==0 => score := 1e-9 (NOT -inf).
//
// R1: 8x8 micro-tile (1 B LDS per FMA, was 2 B at 4x4 -> LDS pipe was 3x
// oversubscribed vs SIMD). Conflict-free transposed staging (row-per-lane),
// split-column B fragments ({4tx, 64+4tx}) to avoid 4-way read conflicts.

#define S_LEN 2048
#define DKV   64
#define NBH   32       // B*H
#define TP    128      // attn_p: score tile edge (q rows == k cols per block)
#define LSTR  (TP + 4) // LDS row stride in floats (132: keeps b128 alignment)
#define CTP   128      // attn_ctx: q rows per block

__global__ __launch_bounds__(256) void attn_p_kernel(
    const float* __restrict__ q, const float* __restrict__ k,
    const int* __restrict__ mask, float* __restrict__ attn,
    float* __restrict__ rowsum)
{
    __shared__ float Qts[DKV][LSTR];   // [kk][q_row]  (transposed)
    __shared__ float Kts[DKV][LSTR];   // [kk][k_col]  (transposed)

    const int kt = blockIdx.x;   // k tile (0..15)
    const int qt = blockIdx.y;   // q tile (0..15)
    const int bh = blockIdx.z;   // b*H + h (0..31)
    const int t  = threadIdx.x;

    // Stage Q,K tiles (128 rows x 64) transposed into LDS.
    // Row-per-lane: lane owns one row-half -> ds_write addresses are
    // consecutive across the wave (conflict-free), vs 8-way conflicts of the
    // old coalesced-f pattern. Global reads are 16B/lane at 256B stride; L1
    // (64 lanes x 64B lines = 4KB live) gives full line utilization.
    {
        const int row = t & 127;
        const int ch  = (t >> 7) * 32;   // which 32-col half
        const float* qr = q + ((size_t)(bh * S_LEN + qt * TP + row)) * DKV + ch;
        const float* kr = k + ((size_t)(bh * S_LEN + kt * TP + row)) * DKV + ch;
#pragma unroll
        for (int j = 0; j < 8; ++j) {
            const int c = ch + 4 * j;
            const float4 a4 = *(const float4*)(qr + 4 * j);
            Qts[c + 0][row] = a4.x; Qts[c + 1][row] = a4.y;
            Qts[c + 2][row] = a4.z; Qts[c + 3][row] = a4.w;
            const float4 b4 = *(const float4*)(kr + 4 * j);
            Kts[c + 0][row] = b4.x; Kts[c + 1][row] = b4.y;
            Kts[c + 2][row] = b4.z; Kts[c + 3][row] = b4.w;
        }
    }
    __syncthreads();

    const int tx = t & 15;       // score col group (16 groups)
    const int ty = t >> 4;       // score row group (16 groups of 8 rows)

    // 8x8 per thread: rows 8*ty..+7, cols {4*tx..+3} u {64+4*tx..+3}.
    // Split B columns: contiguous 8*tx across 16 lanes hits only 4 bank
    // groups (4-way conflict); 4*tx and 64+4*tx each cover all 32 banks 2-way.
    float acc0[8][4] = {};
    float acc1[8][4] = {};
#pragma unroll 8
    for (int kk = 0; kk < DKV; ++kk) {
        const float4 a40 = *(const float4*)&Qts[kk][8 * ty];
        const float4 a41 = *(const float4*)&Qts[kk][8 * ty + 4];
        const float4 b40 = *(const float4*)&Kts[kk][4 * tx];
        const float4 b41 = *(const float4*)&Kts[kk][64 + 4 * tx];
        const float a[8]  = {a40.x, a40.y, a40.z, a40.w, a41.x, a41.y, a41.z, a41.w};
        const float b0[4] = {b40.x, b40.y, b40.z, b40.w};
        const float b1[4] = {b41.x, b41.y, b41.z, b41.w};
#pragma unroll
        for (int i = 0; i < 8; ++i) {
#pragma unroll
            for (int jj = 0; jj < 4; ++jj) {
                acc0[i][jj] = fmaf(a[i], b0[jj], acc0[i][jj]);
                acc1[i][jj] = fmaf(a[i], b1[jj], acc1[i][jj]);
            }
        }
    }

    // Epilogue: scale, mask, exp, store unnormalized P, row partial sums.
    const float scale = 0.125f;  // 1/sqrt(64)
    const int b_idx = bh >> 4;   // bh / H
    const int c0 = kt * TP + 4 * tx;
    const int c1 = c0 + 64;
    float partial[8];
#pragma unroll
    for (int i = 0; i < 8; ++i) {
        const int qr = qt * TP + 8 * ty + i;
        const int* mrow = mask + (size_t)b_idx * S_LEN * S_LEN + (size_t)qr * S_LEN;
        const int4 m0 = *(const int4*)(mrow + c0);
        const int4 m1 = *(const int4*)(mrow + c1);
        float s;
        float4 p0, p1;
        s = acc0[i][0] * scale; if (m0.x == 0) s = 1e-9f; p0.x = __expf(s);
        s = acc0[i][1] * scale; if (m0.y == 0) s = 1e-9f; p0.y = __expf(s);
        s = acc0[i][2] * scale; if (m0.z == 0) s = 1e-9f; p0.z = __expf(s);
        s = acc0[i][3] * scale; if (m0.w == 0) s = 1e-9f; p0.w = __expf(s);
        s = acc1[i][0] * scale; if (m1.x == 0) s = 1e-9f; p1.x = __expf(s);
        s = acc1[i][1] * scale; if (m1.y == 0) s = 1e-9f; p1.y = __expf(s);
        s = acc1[i][2] * scale; if (m1.z == 0) s = 1e-9f; p1.z = __expf(s);
        s = acc1[i][3] * scale; if (m1.w == 0) s = 1e-9f; p1.w = __expf(s);
        float* arow = attn + ((size_t)(bh * S_LEN) + qr) * S_LEN;
        *(float4*)(arow + c0) = p0;
        *(float4*)(arow + c1) = p1;
        partial[i] = ((p0.x + p0.y) + (p0.z + p0.w))
                   + ((p1.x + p1.y) + (p1.z + p1.w));
    }
    // Reduce across the 16 tx lanes (contiguous lane groups within a wave).
#pragma unroll
    for (int i = 0; i < 8; ++i) {
#pragma unroll
        for (int off = 8; off > 0; off >>= 1)
            partial[i] += __shfl_down(partial[i], off, 16);
    }
    if (tx == 0) {
        const int rbase = bh * S_LEN + qt * TP + 8 * ty;
#pragma unroll
        for (int i = 0; i < 8; ++i)
            atomicAdd(&rowsum[rbase + i], partial[i]);
    }
}

__global__ __launch_bounds__(128) void attn_ctx_kernel(
    const float* __restrict__ v, float* __restrict__ attn,
    const float* __restrict__ rowsum, float* __restrict__ ctx)
{
    __shared__ float Pts[DKV][LSTR];      // [kk][q_row] (transposed, normalized P)
    __shared__ float Vs[DKV][DKV + 4];    // [kk][d]

    const int qt = blockIdx.x;   // q tile (0..15)
    const int bh = blockIdx.y;   // 0..31
    const int t  = threadIdx.x;  // 0..127; thread t owns P row (qt*128 + t)
    const int tx = t & 7;        // d col group (8 groups of 8)
    const int ty = t >> 3;       // q row group (16 groups of 8)

    const float rinv = 1.0f / rowsum[bh * S_LEN + qt * CTP + t];
    float* prow = attn + ((size_t)(bh * S_LEN) + qt * CTP + t) * S_LEN;

    float acc[8][8] = {};
    for (int kt = 0; kt < S_LEN / DKV; ++kt) {   // 32 k-tiles of width 64
        // Stage P: each thread streams its own q-row (64 cols = 16 float4):
        // normalize, write back in place, scatter transposed into LDS.
        // ds_write addresses are consecutive across the wave (conflict-free);
        // one scalar rinv per thread, no LDS broadcast needed.
#pragma unroll
        for (int j = 0; j < 16; ++j) {
            float4 p4 = *(const float4*)(prow + kt * DKV + 4 * j);
            p4.x *= rinv; p4.y *= rinv; p4.z *= rinv; p4.w *= rinv;
            *(float4*)(prow + kt * DKV + 4 * j) = p4;   // normalized attention out
            const int c = 4 * j;
            Pts[c + 0][t] = p4.x; Pts[c + 1][t] = p4.y;
            Pts[c + 2][t] = p4.z; Pts[c + 3][t] = p4.w;
        }
        // Stage V tile (64 x 64, contiguous): direct layout, b128 writes.
        const float* vbase = v + (size_t)(bh * S_LEN + kt * DKV) * DKV;
#pragma unroll
        for (int j = 0; j < 8; ++j) {
            const int f  = (t + 128 * j) * 4;
            const int vr = f >> 6;
            const int vc = f & 63;
            *(float4*)&Vs[vr][vc] = *(const float4*)(vbase + f);
        }
        __syncthreads();

        // 8x8 per thread: rows 8*ty..+7, cols 8*tx..+7 (only 8 tx groups ->
        // contiguous-8 reads are 2-way on banks, i.e. free).
#pragma unroll 8
        for (int kk = 0; kk < DKV; ++kk) {
            const float4 a40 = *(const float4*)&Pts[kk][8 * ty];
            const float4 a41 = *(const float4*)&Pts[kk][8 * ty + 4];
            const float4 b40 = *(const float4*)&Vs[kk][8 * tx];
            const float4 b41 = *(const float4*)&Vs[kk][8 * tx + 4];
            const float a[8] = {a40.x, a40.y, a40.z, a40.w, a41.x, a41.y, a41.z, a41.w};
            const float b[8] = {b40.x, b40.y, b40.z, b40.w, b41.x, b41.y, b41.z, b41.w};
#pragma unroll
            for (int i = 0; i < 8; ++i) {
#pragma unroll
                for (int jj = 0; jj < 8; ++jj)
                    acc[i][jj] = fmaf(a[i], b[jj], acc[i][jj]);
            }
        }
        __syncthreads();
    }

#pragma unroll
    for (int i = 0; i < 8; ++i) {
        const int qr = qt * CTP + 8 * ty + i;
        float4 c40, c41;
        c40.x = acc[i][0]; c40.y = acc[i][1]; c40.z = acc[i][2]; c40.w = acc[i][3];
        c41.x = acc[i][4]; c41.y = acc[i][5]; c41.z = acc[i][6]; c41.w = acc[i][7];
        float* crow = ctx + ((size_t)(bh * S_LEN) + qr) * DKV + 8 * tx;
        *(float4*)(crow + 0) = c40;
        *(float4*)(crow + 4) = c41;
    }
}

extern "C" void kernel_launch(void* const* d_in, const int* in_sizes, int n_in,
                              void* d_out, int out_size, void* d_ws, size_t ws_size,
                              hipStream_t stream) {
    const float* q    = (const float*)d_in[0];
    const float* k    = (const float*)d_in[1];
    const float* v    = (const float*)d_in[2];
    const int*   mask = (const int*)d_in[3];

    float* out  = (float*)d_out;
    float* ctx  = out;                                  // (B,H,S,64)
    float* attn = out + (size_t)NBH * S_LEN * DKV;      // (B,H,S,S)
    float* rowsum = (float*)d_ws;                       // NBH*S floats = 256 KB

    hipMemsetAsync(rowsum, 0, (size_t)NBH * S_LEN * sizeof(float), stream);

    attn_p_kernel<<<dim3(S_LEN / TP, S_LEN / TP, NBH), 256, 0, stream>>>(
        q, k, mask, attn, rowsum);
    attn_ctx_kernel<<<dim3(S_LEN / CTP, NBH), 128, 0, stream>>>(
        v, attn, rowsum, ctx);
}